// Round 1
// baseline (12646.788 us; speedup 1.0000x reference)
//
#include <hip/hip_runtime.h>
#include <math.h>

#define BSZ 256
#define NV  4096
#define MC  2048
#define HID 1024
#define FREEN 512
#define NITER 31
#define TOLF 1e-4f

enum { EPI_NONE=0, EPI_BIASRELU=1, EPI_BIAS=2, EPI_ADDMAT=3, EPI_EQ=4 };

// Generic f32 tile GEMM: C[m,n] = sum_k X[m,k] * B[k,n]
//  B = W (NN, TB=false, W is [K,N] row-major)  or  B = W^T (NT, TB=true, W is [N,K] row-major)
// Staging: X tile transposed into As[k][m], B tile into Bs[k][n]; both read as float-vectors.
// RELUIN: apply relu to X elements with global k >= FREEN (P2 operator; FREEN%BK==0 so uniform per tile).
template<int BM,int BN,int BK,int TM,int TN,bool TB,bool RELUIN,int EPI>
__global__ __launch_bounds__(256)
void gemm_k(const float* __restrict__ X, int ldx,
            const float* __restrict__ W, int ldw,
            float* __restrict__ C,
            int K, int N,
            const float* __restrict__ bvec,
            const float* __restrict__ addm, int ldadd,
            const int* __restrict__ guard)
{
  if (guard && guard[0]) return;
  const int t = (int)threadIdx.x;
  const int m0 = (int)blockIdx.y*BM, n0 = (int)blockIdx.x*BN;
  __shared__ float As[BK][BM+4];
  __shared__ float Bs[BK][BN+4];
  constexpr int TX = BN/TN;
  const int tx = t % TX, ty = t / TX;
  constexpr int ALD = (BM*BK)/1024;   // float4 loads per thread (256 thr)
  constexpr int BLD = (BN*BK)/1024;
  float4 pa[ALD], pb[BLD];
  float acc[TM][TN];
  #pragma unroll
  for (int i=0;i<TM;i++)
    #pragma unroll
    for (int j=0;j<TN;j++) acc[i][j]=0.f;

  const int nk = K/BK;

  auto loadA = [&](int kt){
    const int k0 = kt*BK;
    const bool rl = RELUIN && (k0 >= FREEN);
    #pragma unroll
    for (int q=0;q<ALD;q++){
      const int idx = q*256 + t;
      const int r = idx/(BK/4), c4 = (idx%(BK/4))*4;
      float4 v = *reinterpret_cast<const float4*>(&X[(size_t)(m0+r)*ldx + k0 + c4]);
      if (rl){ v.x=fmaxf(v.x,0.f); v.y=fmaxf(v.y,0.f); v.z=fmaxf(v.z,0.f); v.w=fmaxf(v.w,0.f); }
      pa[q]=v;
    }
  };
  auto loadB = [&](int kt){
    const int k0 = kt*BK;
    #pragma unroll
    for (int q=0;q<BLD;q++){
      const int idx = q*256 + t;
      if (TB){
        const int r = idx/(BK/4), c4 = (idx%(BK/4))*4;
        pb[q] = *reinterpret_cast<const float4*>(&W[(size_t)(n0+r)*ldw + k0 + c4]);
      } else {
        const int r = idx/(BN/4), c4 = (idx%(BN/4))*4;
        pb[q] = *reinterpret_cast<const float4*>(&W[(size_t)(k0+r)*ldw + n0 + c4]);
      }
    }
  };
  auto stor = [&](){
    #pragma unroll
    for (int q=0;q<ALD;q++){
      const int idx = q*256 + t;
      const int r = idx/(BK/4), c4 = (idx%(BK/4))*4;
      As[c4+0][r]=pa[q].x; As[c4+1][r]=pa[q].y; As[c4+2][r]=pa[q].z; As[c4+3][r]=pa[q].w;
    }
    #pragma unroll
    for (int q=0;q<BLD;q++){
      const int idx = q*256 + t;
      if (TB){
        const int r = idx/(BK/4), c4 = (idx%(BK/4))*4;
        Bs[c4+0][r]=pb[q].x; Bs[c4+1][r]=pb[q].y; Bs[c4+2][r]=pb[q].z; Bs[c4+3][r]=pb[q].w;
      } else {
        const int r = idx/(BN/4), c4 = (idx%(BN/4))*4;
        *reinterpret_cast<float4*>(&Bs[r][c4]) = pb[q];
      }
    }
  };

  loadA(0); loadB(0);
  for (int kt=0; kt<nk; ++kt){
    __syncthreads();
    stor();
    __syncthreads();
    if (kt+1 < nk){ loadA(kt+1); loadB(kt+1); }   // overlap global latency with compute
    #pragma unroll
    for (int kk=0; kk<BK; ++kk){
      float a[TM], b[TN];
      if constexpr (TM==4) *reinterpret_cast<float4*>(a) = *reinterpret_cast<const float4*>(&As[kk][ty*TM]);
      else                 *reinterpret_cast<float2*>(a) = *reinterpret_cast<const float2*>(&As[kk][ty*TM]);
      if constexpr (TN==4) *reinterpret_cast<float4*>(b) = *reinterpret_cast<const float4*>(&Bs[kk][tx*TN]);
      else                 *reinterpret_cast<float2*>(b) = *reinterpret_cast<const float2*>(&Bs[kk][tx*TN]);
      #pragma unroll
      for (int i=0;i<TM;i++)
        #pragma unroll
        for (int j=0;j<TN;j++)
          acc[i][j] = fmaf(a[i], b[j], acc[i][j]);
    }
  }

  if constexpr (EPI==EPI_EQ){
    // residual = acc - b_primal; per-column sum of |residual| over this block's BM rows
    float csum[TN];
    #pragma unroll
    for (int j=0;j<TN;j++) csum[j]=0.f;
    #pragma unroll
    for (int i=0;i<TM;i++){
      const int r = m0 + ty*TM + i;
      #pragma unroll
      for (int j=0;j<TN;j++){
        const int c = n0 + tx*TN + j;
        const float v = acc[i][j] - addm[(size_t)r*ldadd + c];
        csum[j] += fabsf(v);
      }
    }
    __syncthreads();
    float* red = &As[0][0];          // BN * (BM/TM) floats, fits in As
    constexpr int RY = BM/TM;
    #pragma unroll
    for (int j=0;j<TN;j++) red[(tx*TN+j)*RY + ty] = csum[j];
    __syncthreads();
    if (t < BN){
      float s=0.f;
      #pragma unroll
      for (int y=0;y<RY;y++) s += red[t*RY + y];
      C[(size_t)blockIdx.y*N + n0 + t] = s;   // eqpart[blockY][col]
    }
  } else {
    #pragma unroll
    for (int i=0;i<TM;i++){
      const int r = m0 + ty*TM + i;
      #pragma unroll
      for (int j=0;j<TN;j++){
        const int c = n0 + tx*TN + j;
        float v = acc[i][j];
        if constexpr (EPI==EPI_BIASRELU){ v += bvec[c]; v = fmaxf(v,0.f); }
        if constexpr (EPI==EPI_BIAS)    { v += bvec[c]; }
        if constexpr (EPI==EPI_ADDMAT)  { v += addm[(size_t)r*ldadd + c]; }
        C[(size_t)r*N + c] = v;
      }
    }
  }
}

// In-place LayerNorm over rows of x [BSZ, HID]; one block per row, 4 elems/thread.
__global__ __launch_bounds__(256)
void ln_k(float* __restrict__ x, const float* __restrict__ g, const float* __restrict__ b)
{
  const int row = blockIdx.x, t = threadIdx.x;
  float4 v = *reinterpret_cast<const float4*>(&x[(size_t)row*HID + t*4]);
  __shared__ float sm[256];
  sm[t] = v.x+v.y+v.z+v.w;
  __syncthreads();
  for (int st=128; st>0; st>>=1){ if (t<st) sm[t]+=sm[t+st]; __syncthreads(); }
  const float mu = sm[0]*(1.f/(float)HID);
  __syncthreads();
  const float dx=v.x-mu, dy=v.y-mu, dz=v.z-mu, dw=v.w-mu;
  sm[t] = dx*dx+dy*dy+dz*dz+dw*dw;
  __syncthreads();
  for (int st=128; st>0; st>>=1){ if (t<st) sm[t]+=sm[t+st]; __syncthreads(); }
  const float inv = 1.f/sqrtf(sm[0]*(1.f/(float)HID) + 1e-5f);
  const int c = t*4;
  const float4 gv = *reinterpret_cast<const float4*>(&g[c]);
  const float4 bv = *reinterpret_cast<const float4*>(&b[c]);
  float4 o;
  o.x = dx*inv*gv.x + bv.x; o.y = dy*inv*gv.y + bv.y;
  o.z = dz*inv*gv.z + bv.z; o.w = dw*inv*gv.w + bv.w;
  *reinterpret_cast<float4*>(&x[(size_t)row*HID + c]) = o;
}

// Convergence test: ids [0,2048) -> eq columns (sum 8 row-block partials / 256);
//                   ids [2048, 2048+3584) -> ineq columns of z_new (cols 512..4095).
__global__ __launch_bounds__(256)
void check_k(const float* __restrict__ eqpart, const float* __restrict__ znew,
             int* __restrict__ viol, const int* __restrict__ done)
{
  if (done[0]) return;
  const int id = blockIdx.x*256 + threadIdx.x;
  bool bad;
  if (id < MC){
    float s = 0.f;
    #pragma unroll
    for (int g=0; g<8; g++) s += eqpart[g*MC + id];
    bad = (s*(1.f/(float)BSZ) > TOLF);
  } else {
    const int c = FREEN + (id - MC);
    float s = 0.f;
    for (int r=0; r<BSZ; r++){
      const float v = znew[(size_t)r*NV + c];
      s += (v < 0.f) ? -v : 0.f;
    }
    bad = (s*(1.f/(float)BSZ) > TOLF);
  }
  if (bad) atomicAdd(viol, 1);
}

__global__ void init_k(int* flags){ flags[0]=0; flags[1]=0; flags[2]=0; }  // done, it, viol

__global__ void update_k(int* flags){
  if (!flags[0]){ flags[1] += 1; if (flags[2]==0) flags[0]=1; }
  flags[2] = 0;
}

// Resolve ping-pong parity (z ends in buf[it&1]; buf0 IS the d_out z region) and write proj_num.
__global__ __launch_bounds__(256)
void final_k(const float* __restrict__ buf1, float* __restrict__ out, const int* __restrict__ flags)
{
  const int i = blockIdx.x*256 + threadIdx.x;
  const int k = flags[1];
  if ((k & 1) && i < BSZ*NV) out[i] = buf1[i];
  if (i == 0) out[2*BSZ*NV] = (float)k;
}

extern "C" void kernel_launch(void* const* d_in, const int* in_sizes, int n_in,
                              void* d_out, int out_size, void* d_ws, size_t ws_size,
                              hipStream_t stream)
{
  const float* bp  = (const float*)d_in[0];   // [256,2048]
  const float* w1  = (const float*)d_in[1];   // [2048,1024]
  const float* b1  = (const float*)d_in[2];
  const float* g1  = (const float*)d_in[3];
  const float* be1 = (const float*)d_in[4];
  const float* w2  = (const float*)d_in[5];   // [1024,1024]
  const float* b2  = (const float*)d_in[6];
  const float* g2  = (const float*)d_in[7];
  const float* be2 = (const float*)d_in[8];
  const float* w3  = (const float*)d_in[9];
  const float* b3  = (const float*)d_in[10];
  const float* g3  = (const float*)d_in[11];
  const float* be3 = (const float*)d_in[12];
  const float* wo  = (const float*)d_in[13];  // [1024,4096]
  const float* bo  = (const float*)d_in[14];
  const float* A   = (const float*)d_in[15];  // [2048,4096]
  const float* Wz  = (const float*)d_in[16];  // [4096,4096] (symmetric projector, used as W^T)
  const float* Wb  = (const float*)d_in[17];  // [4096,2048]

  float* out  = (float*)d_out;
  float* z0   = out + (size_t)BSZ*NV;     // second output, also feeds z_init
  float* buf0 = out;                      // z ping-pong buffer 0 lives in d_out

  float* ws     = (float*)d_ws;
  float* tmp1   = ws;                         // 256*1024
  float* tmp2   = tmp1 + (size_t)BSZ*HID;     // 256*1024
  float* BiasM  = tmp2 + (size_t)BSZ*HID;     // 256*4096
  float* buf1   = BiasM + (size_t)BSZ*NV;     // 256*4096
  float* eqpart = buf1 + (size_t)BSZ*NV;      // 8*2048
  int*   flags  = (int*)(eqpart + 8*MC);      // done, it, viol

  const dim3 blk(256);

  hipLaunchKernelGGL(init_k, dim3(1), dim3(1), 0, stream, flags);

  // ---- MLP: h = LN(relu(x@W + b)) x3, then z0 = h@Wout + bout ----
  hipLaunchKernelGGL((gemm_k<64,64,32,4,4,false,false,EPI_BIASRELU>), dim3(HID/64, BSZ/64), blk, 0, stream,
                     bp, MC, w1, HID, tmp1, MC, HID, b1, nullptr, 0, nullptr);
  hipLaunchKernelGGL(ln_k, dim3(BSZ), blk, 0, stream, tmp1, g1, be1);
  hipLaunchKernelGGL((gemm_k<64,64,32,4,4,false,false,EPI_BIASRELU>), dim3(HID/64, BSZ/64), blk, 0, stream,
                     tmp1, HID, w2, HID, tmp2, HID, HID, b2, nullptr, 0, nullptr);
  hipLaunchKernelGGL(ln_k, dim3(BSZ), blk, 0, stream, tmp2, g2, be2);
  hipLaunchKernelGGL((gemm_k<64,64,32,4,4,false,false,EPI_BIASRELU>), dim3(HID/64, BSZ/64), blk, 0, stream,
                     tmp2, HID, w3, HID, tmp1, HID, HID, b3, nullptr, 0, nullptr);
  hipLaunchKernelGGL(ln_k, dim3(BSZ), blk, 0, stream, tmp1, g3, be3);
  hipLaunchKernelGGL((gemm_k<64,64,32,4,4,false,false,EPI_BIAS>), dim3(NV/64, BSZ/64), blk, 0, stream,
                     tmp1, HID, wo, NV, z0, HID, NV, bo, nullptr, 0, nullptr);

  // ---- Bias = b_primal @ WbProj^T ; z_init = Bias + z0 @ WzProj^T ----
  hipLaunchKernelGGL((gemm_k<64,64,32,4,4,true,false,EPI_NONE>), dim3(NV/64, BSZ/64), blk, 0, stream,
                     bp, MC, Wb, MC, BiasM, MC, NV, nullptr, nullptr, 0, nullptr);
  hipLaunchKernelGGL((gemm_k<64,64,32,4,4,true,false,EPI_ADDMAT>), dim3(NV/64, BSZ/64), blk, 0, stream,
                     z0, NV, Wz, NV, buf0, NV, NV, nullptr, BiasM, NV, nullptr);

  // ---- 31 guarded projection iterations ----
  int* done = flags;
  for (int j=1; j<=NITER; ++j){
    float* src = (j&1) ? buf0 : buf1;
    float* dst = (j&1) ? buf1 : buf0;
    // z_new = Bias + P2(z) @ Wp   (relu applied on-the-fly to k >= 512)
    hipLaunchKernelGGL((gemm_k<64,64,32,4,4,true,true,EPI_ADDMAT>), dim3(NV/64, BSZ/64), blk, 0, stream,
                       src, NV, Wz, NV, dst, NV, NV, nullptr, BiasM, NV, done);
    // eq partials: per-column sum over 32-row blocks of |z_new@A^T - b_primal|
    hipLaunchKernelGGL((gemm_k<32,64,32,2,4,true,false,EPI_EQ>), dim3(MC/64, BSZ/32), blk, 0, stream,
                       dst, NV, A, NV, eqpart, NV, MC, nullptr, bp, MC, done);
    hipLaunchKernelGGL(check_k, dim3((MC + (NV-FREEN))/256), blk, 0, stream, eqpart, dst, flags+2, done);
    hipLaunchKernelGGL(update_k, dim3(1), dim3(1), 0, stream, flags);
  }

  hipLaunchKernelGGL(final_k, dim3((BSZ*NV)/256), blk, 0, stream, buf1, out, flags);

  (void)in_sizes; (void)n_in; (void)out_size; (void)ws_size;
}

// Round 3
// 8387.263 us; speedup vs baseline: 1.5079x; 1.5079x over previous
//
#include <hip/hip_runtime.h>
#include <math.h>

#define BSZ 256
#define NV  4096
#define MC  2048
#define HID 1024
#define FREEN 512
#define NITER 31
#define TOLF 1e-4f

typedef _Float16 half8 __attribute__((ext_vector_type(8)));
typedef _Float16 half4 __attribute__((ext_vector_type(4)));
typedef float f32x16 __attribute__((ext_vector_type(16)));

enum { EPI_NONE=0, EPI_BIASRELU=1, EPI_BIAS=2, EPI_ADDMAT=3, EPI_EQ=4 };

// ---------------- f32 vector-ALU GEMM (prologue + fallback path) ----------------
template<int BM,int BN,int BK,int TM,int TN,bool TB,bool RELUIN,int EPI>
__global__ __launch_bounds__(256)
void gemm_k(const float* __restrict__ X, int ldx,
            const float* __restrict__ W, int ldw,
            float* __restrict__ C,
            int K, int N,
            const float* __restrict__ bvec,
            const float* __restrict__ addm, int ldadd,
            const int* __restrict__ guard)
{
  if (guard && guard[0]) return;
  const int t = (int)threadIdx.x;
  const int m0 = (int)blockIdx.y*BM, n0 = (int)blockIdx.x*BN;
  __shared__ float As[BK][BM+4];
  __shared__ float Bs[BK][BN+4];
  constexpr int TX = BN/TN;
  const int tx = t % TX, ty = t / TX;
  constexpr int ALD = (BM*BK)/1024;
  constexpr int BLD = (BN*BK)/1024;
  float4 pa[ALD], pb[BLD];
  float acc[TM][TN];
  #pragma unroll
  for (int i=0;i<TM;i++)
    #pragma unroll
    for (int j=0;j<TN;j++) acc[i][j]=0.f;

  const int nk = K/BK;

  auto loadA = [&](int kt){
    const int k0 = kt*BK;
    const bool rl = RELUIN && (k0 >= FREEN);
    #pragma unroll
    for (int q=0;q<ALD;q++){
      const int idx = q*256 + t;
      const int r = idx/(BK/4), c4 = (idx%(BK/4))*4;
      float4 v = *reinterpret_cast<const float4*>(&X[(size_t)(m0+r)*ldx + k0 + c4]);
      if (rl){ v.x=fmaxf(v.x,0.f); v.y=fmaxf(v.y,0.f); v.z=fmaxf(v.z,0.f); v.w=fmaxf(v.w,0.f); }
      pa[q]=v;
    }
  };
  auto loadB = [&](int kt){
    const int k0 = kt*BK;
    #pragma unroll
    for (int q=0;q<BLD;q++){
      const int idx = q*256 + t;
      if (TB){
        const int r = idx/(BK/4), c4 = (idx%(BK/4))*4;
        pb[q] = *reinterpret_cast<const float4*>(&W[(size_t)(n0+r)*ldw + k0 + c4]);
      } else {
        const int r = idx/(BN/4), c4 = (idx%(BN/4))*4;
        pb[q] = *reinterpret_cast<const float4*>(&W[(size_t)(k0+r)*ldw + n0 + c4]);
      }
    }
  };
  auto stor = [&](){
    #pragma unroll
    for (int q=0;q<ALD;q++){
      const int idx = q*256 + t;
      const int r = idx/(BK/4), c4 = (idx%(BK/4))*4;
      As[c4+0][r]=pa[q].x; As[c4+1][r]=pa[q].y; As[c4+2][r]=pa[q].z; As[c4+3][r]=pa[q].w;
    }
    #pragma unroll
    for (int q=0;q<BLD;q++){
      const int idx = q*256 + t;
      if (TB){
        const int r = idx/(BK/4), c4 = (idx%(BK/4))*4;
        Bs[c4+0][r]=pb[q].x; Bs[c4+1][r]=pb[q].y; Bs[c4+2][r]=pb[q].z; Bs[c4+3][r]=pb[q].w;
      } else {
        const int r = idx/(BN/4), c4 = (idx%(BN/4))*4;
        *reinterpret_cast<float4*>(&Bs[r][c4]) = pb[q];
      }
    }
  };

  loadA(0); loadB(0);
  for (int kt=0; kt<nk; ++kt){
    __syncthreads();
    stor();
    __syncthreads();
    if (kt+1 < nk){ loadA(kt+1); loadB(kt+1); }
    #pragma unroll
    for (int kk=0; kk<BK; ++kk){
      float a[TM], b[TN];
      if constexpr (TM==4) *reinterpret_cast<float4*>(a) = *reinterpret_cast<const float4*>(&As[kk][ty*TM]);
      else                 *reinterpret_cast<float2*>(a) = *reinterpret_cast<const float2*>(&As[kk][ty*TM]);
      if constexpr (TN==4) *reinterpret_cast<float4*>(b) = *reinterpret_cast<const float4*>(&Bs[kk][tx*TN]);
      else                 *reinterpret_cast<float2*>(b) = *reinterpret_cast<const float2*>(&Bs[kk][tx*TN]);
      #pragma unroll
      for (int i=0;i<TM;i++)
        #pragma unroll
        for (int j=0;j<TN;j++)
          acc[i][j] = fmaf(a[i], b[j], acc[i][j]);
    }
  }

  if constexpr (EPI==EPI_EQ){
    float csum[TN];
    #pragma unroll
    for (int j=0;j<TN;j++) csum[j]=0.f;
    #pragma unroll
    for (int i=0;i<TM;i++){
      const int r = m0 + ty*TM + i;
      #pragma unroll
      for (int j=0;j<TN;j++){
        const int c = n0 + tx*TN + j;
        const float v = acc[i][j] - addm[(size_t)r*ldadd + c];
        csum[j] += fabsf(v);
      }
    }
    __syncthreads();
    float* red = &As[0][0];
    constexpr int RY = BM/TM;
    #pragma unroll
    for (int j=0;j<TN;j++) red[(tx*TN+j)*RY + ty] = csum[j];
    __syncthreads();
    if (t < BN){
      float s=0.f;
      #pragma unroll
      for (int y=0;y<RY;y++) s += red[t*RY + y];
      C[(size_t)blockIdx.y*N + n0 + t] = s;
    }
  } else {
    #pragma unroll
    for (int i=0;i<TM;i++){
      const int r = m0 + ty*TM + i;
      #pragma unroll
      for (int j=0;j<TN;j++){
        const int c = n0 + tx*TN + j;
        float v = acc[i][j];
        if constexpr (EPI==EPI_BIASRELU){ v += bvec[c]; v = fmaxf(v,0.f); }
        if constexpr (EPI==EPI_BIAS)    { v += bvec[c]; }
        if constexpr (EPI==EPI_ADDMAT)  { v += addm[(size_t)r*ldadd + c]; }
        C[(size_t)r*N + c] = v;
      }
    }
  }
}

// ---------------- fp16x2 split helpers ----------------
__device__ __forceinline__ void split_f32(float v, _Float16& h, _Float16& l){
  float hf = 0.f;
  _Float16 hh = (_Float16)0.f;
  if (fabsf(v) >= 6.103515625e-05f) { hh = (_Float16)v; hf = (float)hh; }
  h = hh;
  l = (_Float16)((v - hf) * 2048.0f);
}

// src f32 [n4*4] -> hi/lo fp16 arrays (lo scaled by 2048)
__global__ __launch_bounds__(256)
void split_k(const float* __restrict__ src, _Float16* __restrict__ h,
             _Float16* __restrict__ l, int n4)
{
  const int i = blockIdx.x*256 + threadIdx.x;
  if (i >= n4) return;
  const float4 v = *reinterpret_cast<const float4*>(&src[(size_t)i*4]);
  half4 hh, ll;
  _Float16 a, b;
  split_f32(v.x,a,b); hh.x=a; ll.x=b;
  split_f32(v.y,a,b); hh.y=a; ll.y=b;
  split_f32(v.z,a,b); hh.z=a; ll.z=b;
  split_f32(v.w,a,b); hh.w=a; ll.w=b;
  *reinterpret_cast<half4*>(&h[(size_t)i*4]) = hh;
  *reinterpret_cast<half4*>(&l[(size_t)i*4]) = ll;
}

// ---------------- fp16x2 MFMA GEMM: C = Aop @ B^T  (both operands [rows][K] k-contiguous) ----
// BM=BN=64, BK=64, 256 threads = 4 waves (2x2), wave = one 32x32x16 frag position.
// Value model: X = Xh + Xl/2048 ; C = acc0 + (acc1+acc2)/2048.
template<bool RELUIN, int EPI>
__global__ __launch_bounds__(256)
void gemm16_k(const _Float16* __restrict__ Ahg, const _Float16* __restrict__ Alg,
              const _Float16* __restrict__ Bhg, const _Float16* __restrict__ Blg,
              int K, int N,
              float* __restrict__ Cf,                       // ADDMAT: z_new f32 ; EQ: eqpart
              _Float16* __restrict__ Ch, _Float16* __restrict__ Cl,  // ADDMAT: z_new pair
              const float* __restrict__ addm,               // ADDMAT: BiasM ; EQ: b_primal (ld = N)
              const int* __restrict__ guard)
{
  if (guard && guard[0]) return;
  const int t = (int)threadIdx.x;
  const int n0 = (int)blockIdx.x*64, m0 = (int)blockIdx.y*64;
  __shared__ _Float16 Ah[64][64], Al[64][64], Bh[64][64], Bl[64][64];
  __shared__ float red[2][64];
  const int lane = t & 63, wid = t >> 6;
  const int wr = wid >> 1, wc = wid & 1, lg = lane >> 5;
  const int mr = wr*32 + (lane & 31);   // A row within block tile
  const int nr = wc*32 + (lane & 31);   // B row (output col) within block tile

  f32x16 acc0, acc1, acc2;
  #pragma unroll
  for (int i=0;i<16;i++){ acc0[i]=0.f; acc1[i]=0.f; acc2[i]=0.f; }

  float4 ra_h[2], ra_l[2], rb_h[2], rb_l[2];

  auto gload = [&](int kt){
    const int k0 = kt*64;
    #pragma unroll
    for (int q=0;q<2;q++){
      const int idx = q*256 + t;
      const int r = idx>>3, ch = idx&7;
      const size_t offa = (size_t)(m0 + r)*K + k0 + ch*8;
      ra_h[q] = *reinterpret_cast<const float4*>(&Ahg[offa]);
      ra_l[q] = *reinterpret_cast<const float4*>(&Alg[offa]);
      const size_t offb = (size_t)(n0 + r)*K + k0 + ch*8;
      rb_h[q] = *reinterpret_cast<const float4*>(&Bhg[offb]);
      rb_l[q] = *reinterpret_cast<const float4*>(&Blg[offb]);
    }
  };
  auto sstore = [&](int kt){
    const bool rl = RELUIN && (kt*64 >= FREEN);
    #pragma unroll
    for (int q=0;q<2;q++){
      const int idx = q*256 + t;
      const int r = idx>>3, ch = idx&7;
      float4 vh = ra_h[q], vl = ra_l[q];
      if (rl){
        half8 hh = *reinterpret_cast<half8*>(&vh);
        half8 ll = *reinterpret_cast<half8*>(&vl);
        #pragma unroll
        for (int j=0;j<8;j++){
          const _Float16 h = hh[j], l = ll[j];
          if (h < (_Float16)0.f || (h == (_Float16)0.f && l < (_Float16)0.f)){
            hh[j] = (_Float16)0.f; ll[j] = (_Float16)0.f;
          }
        }
        vh = *reinterpret_cast<float4*>(&hh);
        vl = *reinterpret_cast<float4*>(&ll);
      }
      const int sc = (ch ^ (r&7))*8;     // XOR swizzle on 16B chunks
      *reinterpret_cast<float4*>(&Ah[r][sc]) = vh;
      *reinterpret_cast<float4*>(&Al[r][sc]) = vl;
      *reinterpret_cast<float4*>(&Bh[r][sc]) = rb_h[q];
      *reinterpret_cast<float4*>(&Bl[r][sc]) = rb_l[q];
    }
  };

  gload(0);
  const int nk = K/64;
  for (int kt=0; kt<nk; ++kt){
    __syncthreads();
    sstore(kt);
    __syncthreads();
    if (kt+1 < nk) gload(kt+1);
    #pragma unroll
    for (int s=0;s<4;s++){
      const int ca = ((s*2+lg) ^ (mr&7))*8;
      const int cb = ((s*2+lg) ^ (nr&7))*8;
      const half8 ah = *reinterpret_cast<const half8*>(&Ah[mr][ca]);
      const half8 al = *reinterpret_cast<const half8*>(&Al[mr][ca]);
      const half8 bh = *reinterpret_cast<const half8*>(&Bh[nr][cb]);
      const half8 bl = *reinterpret_cast<const half8*>(&Bl[nr][cb]);
      acc0 = __builtin_amdgcn_mfma_f32_32x32x16_f16(ah, bh, acc0, 0, 0, 0);
      acc1 = __builtin_amdgcn_mfma_f32_32x32x16_f16(ah, bl, acc1, 0, 0, 0);
      acc2 = __builtin_amdgcn_mfma_f32_32x32x16_f16(al, bh, acc2, 0, 0, 0);
    }
  }

  if constexpr (EPI == EPI_EQ){
    float s = 0.f;
    #pragma unroll
    for (int r16=0;r16<16;r16++){
      const int row = (r16&3) + 8*(r16>>2) + 4*lg;   // verified 32x32 C/D mapping
      const size_t gm = m0 + wr*32 + row;
      const int gn = n0 + wc*32 + (lane&31);
      float v = acc0[r16] + (acc1[r16]+acc2[r16])*(1.f/2048.f);
      v -= addm[gm*(size_t)N + gn];
      s += fabsf(v);
    }
    s += __shfl_xor(s, 32, 64);
    __syncthreads();
    if (lane < 32) red[wr][wc*32 + lane] = s;
    __syncthreads();
    if (t < 64) Cf[(size_t)blockIdx.y*N + n0 + t] = red[0][t] + red[1][t];
  } else {  // EPI_ADDMAT
    #pragma unroll
    for (int r16=0;r16<16;r16++){
      const int row = (r16&3) + 8*(r16>>2) + 4*lg;
      const size_t gm = m0 + wr*32 + row;
      const int gn = n0 + wc*32 + (lane&31);
      float v = acc0[r16] + (acc1[r16]+acc2[r16])*(1.f/2048.f);
      v += addm[gm*(size_t)N + gn];
      Cf[gm*(size_t)N + gn] = v;
      _Float16 h, l;
      split_f32(v, h, l);
      Ch[gm*(size_t)N + gn] = h;
      Cl[gm*(size_t)N + gn] = l;
    }
  }
}

// ---------------- LayerNorm ----------------
__global__ __launch_bounds__(256)
void ln_k(float* __restrict__ x, const float* __restrict__ g, const float* __restrict__ b)
{
  const int row = blockIdx.x, t = threadIdx.x;
  float4 v = *reinterpret_cast<const float4*>(&x[(size_t)row*HID + t*4]);
  __shared__ float sm[256];
  sm[t] = v.x+v.y+v.z+v.w;
  __syncthreads();
  for (int st=128; st>0; st>>=1){ if (t<st) sm[t]+=sm[t+st]; __syncthreads(); }
  const float mu = sm[0]*(1.f/(float)HID);
  __syncthreads();
  const float dx=v.x-mu, dy=v.y-mu, dz=v.z-mu, dw=v.w-mu;
  sm[t] = dx*dx+dy*dy+dz*dz+dw*dw;
  __syncthreads();
  for (int st=128; st>0; st>>=1){ if (t<st) sm[t]+=sm[t+st]; __syncthreads(); }
  const float inv = 1.f/sqrtf(sm[0]*(1.f/(float)HID) + 1e-5f);
  const int c = t*4;
  const float4 gv = *reinterpret_cast<const float4*>(&g[c]);
  const float4 bv = *reinterpret_cast<const float4*>(&b[c]);
  float4 o;
  o.x = dx*inv*gv.x + bv.x; o.y = dy*inv*gv.y + bv.y;
  o.z = dz*inv*gv.z + bv.z; o.w = dw*inv*gv.w + bv.w;
  *reinterpret_cast<float4*>(&x[(size_t)row*HID + c]) = o;
}

// ---------------- convergence machinery ----------------
__global__ __launch_bounds__(256)
void check_k(const float* __restrict__ eqpart, const float* __restrict__ znew,
             int* __restrict__ viol, const int* __restrict__ done, int ngroups)
{
  if (done[0]) return;
  const int id = blockIdx.x*256 + threadIdx.x;
  bool bad;
  if (id < MC){
    float s = 0.f;
    for (int g=0; g<ngroups; g++) s += eqpart[g*MC + id];
    bad = (s*(1.f/(float)BSZ) > TOLF);
  } else {
    const int c = FREEN + (id - MC);
    float s = 0.f;
    for (int r=0; r<BSZ; r++){
      const float v = znew[(size_t)r*NV + c];
      s += (v < 0.f) ? -v : 0.f;
    }
    bad = (s*(1.f/(float)BSZ) > TOLF);
  }
  if (bad) atomicAdd(viol, 1);
}

__global__ void init_k(int* flags){ flags[0]=0; flags[1]=0; flags[2]=0; }

__global__ void update_k(int* flags){
  if (!flags[0]){ flags[1] += 1; if (flags[2]==0) flags[0]=1; }
  flags[2] = 0;
}

__global__ __launch_bounds__(256)
void final_k(const float* __restrict__ buf1, float* __restrict__ out, const int* __restrict__ flags)
{
  const int i = blockIdx.x*256 + threadIdx.x;
  const int k = flags[1];
  if ((k & 1) && i < BSZ*NV) out[i] = buf1[i];
  if (i == 0) out[2*BSZ*NV] = (float)k;
}

// ---------------- host launch ----------------
extern "C" void kernel_launch(void* const* d_in, const int* in_sizes, int n_in,
                              void* d_out, int out_size, void* d_ws, size_t ws_size,
                              hipStream_t stream)
{
  const float* bp  = (const float*)d_in[0];
  const float* w1  = (const float*)d_in[1];
  const float* b1  = (const float*)d_in[2];
  const float* g1  = (const float*)d_in[3];
  const float* be1 = (const float*)d_in[4];
  const float* w2  = (const float*)d_in[5];
  const float* b2  = (const float*)d_in[6];
  const float* g2  = (const float*)d_in[7];
  const float* be2 = (const float*)d_in[8];
  const float* w3  = (const float*)d_in[9];
  const float* b3  = (const float*)d_in[10];
  const float* g3  = (const float*)d_in[11];
  const float* be3 = (const float*)d_in[12];
  const float* wo  = (const float*)d_in[13];
  const float* bo  = (const float*)d_in[14];
  const float* A   = (const float*)d_in[15];
  const float* Wz  = (const float*)d_in[16];
  const float* Wb  = (const float*)d_in[17];

  float* out  = (float*)d_out;
  float* z0   = out + (size_t)BSZ*NV;
  float* buf0 = out;

  float* ws     = (float*)d_ws;
  float* tmp1   = ws;
  float* tmp2   = tmp1 + (size_t)BSZ*HID;
  float* BiasM  = tmp2 + (size_t)BSZ*HID;
  float* buf1   = BiasM + (size_t)BSZ*NV;
  float* eqpart = buf1 + (size_t)BSZ*NV;          // 8*MC floats (both paths)
  int*   flags  = (int*)(eqpart + 8*MC);          // 4 ints

  _Float16* Wzh = (_Float16*)(flags + 4);
  _Float16* Wzl = Wzh + (size_t)NV*NV;
  _Float16* Amh = Wzl + (size_t)NV*NV;
  _Float16* Aml = Amh + (size_t)MC*NV;
  _Float16* zh0 = Aml + (size_t)MC*NV;
  _Float16* zl0 = zh0 + (size_t)BSZ*NV;
  _Float16* zh1 = zl0 + (size_t)BSZ*NV;
  _Float16* zl1 = zh1 + (size_t)BSZ*NV;
  const size_t need = (size_t)((char*)(zl1 + (size_t)BSZ*NV) - (char*)d_ws);
  const bool fp16path = (ws_size >= need);

  const dim3 blk(256);

  hipLaunchKernelGGL(init_k, dim3(1), dim3(1), 0, stream, flags);

  // ---- MLP + projection-setup (f32, one-time) ----
  hipLaunchKernelGGL((gemm_k<64,64,32,4,4,false,false,EPI_BIASRELU>), dim3(HID/64, BSZ/64), blk, 0, stream,
                     bp, MC, w1, HID, tmp1, MC, HID, b1, nullptr, 0, nullptr);
  hipLaunchKernelGGL(ln_k, dim3(BSZ), blk, 0, stream, tmp1, g1, be1);
  hipLaunchKernelGGL((gemm_k<64,64,32,4,4,false,false,EPI_BIASRELU>), dim3(HID/64, BSZ/64), blk, 0, stream,
                     tmp1, HID, w2, HID, tmp2, HID, HID, b2, nullptr, 0, nullptr);
  hipLaunchKernelGGL(ln_k, dim3(BSZ), blk, 0, stream, tmp2, g2, be2);
  hipLaunchKernelGGL((gemm_k<64,64,32,4,4,false,false,EPI_BIASRELU>), dim3(HID/64, BSZ/64), blk, 0, stream,
                     tmp2, HID, w3, HID, tmp1, HID, HID, b3, nullptr, 0, nullptr);
  hipLaunchKernelGGL(ln_k, dim3(BSZ), blk, 0, stream, tmp1, g3, be3);
  hipLaunchKernelGGL((gemm_k<64,64,32,4,4,false,false,EPI_BIAS>), dim3(NV/64, BSZ/64), blk, 0, stream,
                     tmp1, HID, wo, NV, z0, HID, NV, bo, nullptr, 0, nullptr);
  hipLaunchKernelGGL((gemm_k<64,64,32,4,4,true,false,EPI_NONE>), dim3(NV/64, BSZ/64), blk, 0, stream,
                     bp, MC, Wb, MC, BiasM, MC, NV, nullptr, nullptr, 0, nullptr);
  hipLaunchKernelGGL((gemm_k<64,64,32,4,4,true,false,EPI_ADDMAT>), dim3(NV/64, BSZ/64), blk, 0, stream,
                     z0, NV, Wz, NV, buf0, NV, NV, nullptr, BiasM, NV, nullptr);

  if (fp16path){
    // one-time fp16x2 splits of the constant matrices + z_init
    hipLaunchKernelGGL(split_k, dim3((NV*(size_t)NV)/1024), blk, 0, stream, Wz, Wzh, Wzl, (int)((NV*(size_t)NV)/4));
    hipLaunchKernelGGL(split_k, dim3((MC*(size_t)NV)/1024), blk, 0, stream, A,  Amh, Aml, (int)((MC*(size_t)NV)/4));
    hipLaunchKernelGGL(split_k, dim3((BSZ*(size_t)NV)/1024), blk, 0, stream, buf0, zh0, zl0, (int)((BSZ*(size_t)NV)/4));

    for (int j=1; j<=NITER; ++j){
      _Float16* sh = (j&1) ? zh0 : zh1;
      _Float16* sl = (j&1) ? zl0 : zl1;
      _Float16* dh = (j&1) ? zh1 : zh0;
      _Float16* dl = (j&1) ? zl1 : zl0;
      float* dstf  = (j&1) ? buf1 : buf0;
      // z_new = Bias + P2(z) @ Wp   (MFMA fp16x2; relu on pair during staging for k>=512)
      hipLaunchKernelGGL((gemm16_k<true,EPI_ADDMAT>), dim3(NV/64, BSZ/64), blk, 0, stream,
                         sh, sl, Wzh, Wzl, NV, NV, dstf, dh, dl, BiasM, flags);
      // eq partials: per-column sums of |z_new @ A^T - b| over 64-row blocks
      hipLaunchKernelGGL((gemm16_k<false,EPI_EQ>), dim3(MC/64, BSZ/64), blk, 0, stream,
                         dh, dl, Amh, Aml, NV, MC, eqpart, nullptr, nullptr, bp, flags);
      hipLaunchKernelGGL(check_k, dim3((MC + (NV-FREEN))/256), blk, 0, stream, eqpart, dstf, flags+2, flags, 4);
      hipLaunchKernelGGL(update_k, dim3(1), dim3(1), 0, stream, flags);
    }
  } else {
    // fallback: proven f32 loop (round 1)
    for (int j=1; j<=NITER; ++j){
      float* src = (j&1) ? buf0 : buf1;
      float* dst = (j&1) ? buf1 : buf0;
      hipLaunchKernelGGL((gemm_k<64,64,32,4,4,true,true,EPI_ADDMAT>), dim3(NV/64, BSZ/64), blk, 0, stream,
                         src, NV, Wz, NV, dst, NV, NV, nullptr, BiasM, NV, flags);
      hipLaunchKernelGGL((gemm_k<32,64,32,2,4,true,false,EPI_EQ>), dim3(MC/64, BSZ/32), blk, 0, stream,
                         dst, NV, A, NV, eqpart, NV, MC, nullptr, bp, MC, flags);
      hipLaunchKernelGGL(check_k, dim3((MC + (NV-FREEN))/256), blk, 0, stream, eqpart, dst, flags+2, flags, 8);
      hipLaunchKernelGGL(update_k, dim3(1), dim3(1), 0, stream, flags);
    }
  }

  hipLaunchKernelGGL(final_k, dim3((BSZ*NV)/256), blk, 0, stream, buf1, out, flags);

  (void)in_sizes; (void)n_in; (void)out_size; (void)ws_size;
}

// Round 4
// 7885.278 us; speedup vs baseline: 1.6038x; 1.0637x over previous
//
#include <hip/hip_runtime.h>
#include <math.h>

#define BSZ 256
#define NV  4096
#define MC  2048
#define HID 1024
#define FREEN 512
#define NITER 31
#define TOLF 1e-4f

typedef _Float16 half8 __attribute__((ext_vector_type(8)));
typedef _Float16 half4 __attribute__((ext_vector_type(4)));
typedef float f32x16 __attribute__((ext_vector_type(16)));

enum { EPI_NONE=0, EPI_BIASRELU=1, EPI_BIAS=2, EPI_ADDMAT=3, EPI_EQ=4 };

// ---------------- f32 vector-ALU GEMM (prologue + fallback path) ----------------
template<int BM,int BN,int BK,int TM,int TN,bool TB,bool RELUIN,int EPI>
__global__ __launch_bounds__(256)
void gemm_k(const float* __restrict__ X, int ldx,
            const float* __restrict__ W, int ldw,
            float* __restrict__ C,
            int K, int N,
            const float* __restrict__ bvec,
            const float* __restrict__ addm, int ldadd,
            const int* __restrict__ guard)
{
  if (guard && guard[0]) return;
  const int t = (int)threadIdx.x;
  const int m0 = (int)blockIdx.y*BM, n0 = (int)blockIdx.x*BN;
  __shared__ float As[BK][BM+4];
  __shared__ float Bs[BK][BN+4];
  constexpr int TX = BN/TN;
  const int tx = t % TX, ty = t / TX;
  constexpr int ALD = (BM*BK)/1024;
  constexpr int BLD = (BN*BK)/1024;
  float4 pa[ALD], pb[BLD];
  float acc[TM][TN];
  #pragma unroll
  for (int i=0;i<TM;i++)
    #pragma unroll
    for (int j=0;j<TN;j++) acc[i][j]=0.f;

  const int nk = K/BK;

  auto loadA = [&](int kt){
    const int k0 = kt*BK;
    const bool rl = RELUIN && (k0 >= FREEN);
    #pragma unroll
    for (int q=0;q<ALD;q++){
      const int idx = q*256 + t;
      const int r = idx/(BK/4), c4 = (idx%(BK/4))*4;
      float4 v = *reinterpret_cast<const float4*>(&X[(size_t)(m0+r)*ldx + k0 + c4]);
      if (rl){ v.x=fmaxf(v.x,0.f); v.y=fmaxf(v.y,0.f); v.z=fmaxf(v.z,0.f); v.w=fmaxf(v.w,0.f); }
      pa[q]=v;
    }
  };
  auto loadB = [&](int kt){
    const int k0 = kt*BK;
    #pragma unroll
    for (int q=0;q<BLD;q++){
      const int idx = q*256 + t;
      if (TB){
        const int r = idx/(BK/4), c4 = (idx%(BK/4))*4;
        pb[q] = *reinterpret_cast<const float4*>(&W[(size_t)(n0+r)*ldw + k0 + c4]);
      } else {
        const int r = idx/(BN/4), c4 = (idx%(BN/4))*4;
        pb[q] = *reinterpret_cast<const float4*>(&W[(size_t)(k0+r)*ldw + n0 + c4]);
      }
    }
  };
  auto stor = [&](){
    #pragma unroll
    for (int q=0;q<ALD;q++){
      const int idx = q*256 + t;
      const int r = idx/(BK/4), c4 = (idx%(BK/4))*4;
      As[c4+0][r]=pa[q].x; As[c4+1][r]=pa[q].y; As[c4+2][r]=pa[q].z; As[c4+3][r]=pa[q].w;
    }
    #pragma unroll
    for (int q=0;q<BLD;q++){
      const int idx = q*256 + t;
      if (TB){
        const int r = idx/(BK/4), c4 = (idx%(BK/4))*4;
        Bs[c4+0][r]=pb[q].x; Bs[c4+1][r]=pb[q].y; Bs[c4+2][r]=pb[q].z; Bs[c4+3][r]=pb[q].w;
      } else {
        const int r = idx/(BN/4), c4 = (idx%(BN/4))*4;
        *reinterpret_cast<float4*>(&Bs[r][c4]) = pb[q];
      }
    }
  };

  loadA(0); loadB(0);
  for (int kt=0; kt<nk; ++kt){
    __syncthreads();
    stor();
    __syncthreads();
    if (kt+1 < nk){ loadA(kt+1); loadB(kt+1); }
    #pragma unroll
    for (int kk=0; kk<BK; ++kk){
      float a[TM], b[TN];
      if constexpr (TM==4) *reinterpret_cast<float4*>(a) = *reinterpret_cast<const float4*>(&As[kk][ty*TM]);
      else                 *reinterpret_cast<float2*>(a) = *reinterpret_cast<const float2*>(&As[kk][ty*TM]);
      if constexpr (TN==4) *reinterpret_cast<float4*>(b) = *reinterpret_cast<const float4*>(&Bs[kk][tx*TN]);
      else                 *reinterpret_cast<float2*>(b) = *reinterpret_cast<const float2*>(&Bs[kk][tx*TN]);
      #pragma unroll
      for (int i=0;i<TM;i++)
        #pragma unroll
        for (int j=0;j<TN;j++)
          acc[i][j] = fmaf(a[i], b[j], acc[i][j]);
    }
  }

  if constexpr (EPI==EPI_EQ){
    float csum[TN];
    #pragma unroll
    for (int j=0;j<TN;j++) csum[j]=0.f;
    #pragma unroll
    for (int i=0;i<TM;i++){
      const int r = m0 + ty*TM + i;
      #pragma unroll
      for (int j=0;j<TN;j++){
        const int c = n0 + tx*TN + j;
        const float v = acc[i][j] - addm[(size_t)r*ldadd + c];
        csum[j] += fabsf(v);
      }
    }
    __syncthreads();
    float* red = &As[0][0];
    constexpr int RY = BM/TM;
    #pragma unroll
    for (int j=0;j<TN;j++) red[(tx*TN+j)*RY + ty] = csum[j];
    __syncthreads();
    if (t < BN){
      float s=0.f;
      #pragma unroll
      for (int y=0;y<RY;y++) s += red[t*RY + y];
      C[(size_t)blockIdx.y*N + n0 + t] = s;
    }
  } else {
    #pragma unroll
    for (int i=0;i<TM;i++){
      const int r = m0 + ty*TM + i;
      #pragma unroll
      for (int j=0;j<TN;j++){
        const int c = n0 + tx*TN + j;
        float v = acc[i][j];
        if constexpr (EPI==EPI_BIASRELU){ v += bvec[c]; v = fmaxf(v,0.f); }
        if constexpr (EPI==EPI_BIAS)    { v += bvec[c]; }
        if constexpr (EPI==EPI_ADDMAT)  { v += addm[(size_t)r*ldadd + c]; }
        C[(size_t)r*N + c] = v;
      }
    }
  }
}

// ---------------- fp16x2 split helpers ----------------
__device__ __forceinline__ void split_f32(float v, _Float16& h, _Float16& l){
  float hf = 0.f;
  _Float16 hh = (_Float16)0.f;
  if (fabsf(v) >= 6.103515625e-05f) { hh = (_Float16)v; hf = (float)hh; }
  h = hh;
  l = (_Float16)((v - hf) * 2048.0f);
}

__global__ __launch_bounds__(256)
void split_k(const float* __restrict__ src, _Float16* __restrict__ h,
             _Float16* __restrict__ l, int n4)
{
  const int i = blockIdx.x*256 + threadIdx.x;
  if (i >= n4) return;
  const float4 v = *reinterpret_cast<const float4*>(&src[(size_t)i*4]);
  half4 hh, ll;
  _Float16 a, b;
  split_f32(v.x,a,b); hh.x=a; ll.x=b;
  split_f32(v.y,a,b); hh.y=a; ll.y=b;
  split_f32(v.z,a,b); hh.z=a; ll.z=b;
  split_f32(v.w,a,b); hh.w=a; ll.w=b;
  *reinterpret_cast<half4*>(&h[(size_t)i*4]) = hh;
  *reinterpret_cast<half4*>(&l[(size_t)i*4]) = ll;
}

// ---------------- fused fp16x2 MFMA dispatch ----------------
// Grid (96, 2, 2): blockIdx.x<32 -> EQ tile (B = A-matrix, full K, colsum-|resid| epilogue,
//                  only z==0; dispatched FIRST since they run 2x longer);
//                  blockIdx.x>=32 -> PROJ tile (B = WzProj, K split by blockIdx.z, partial-write).
// Tile 128x64, 4 waves, each wave owns 2 m-frags x 1 n-frag of 32x32x16.
__global__ __launch_bounds__(256)
void fused16_k(const _Float16* __restrict__ zh, const _Float16* __restrict__ zl,
               const _Float16* __restrict__ Wzh, const _Float16* __restrict__ Wzl,
               const _Float16* __restrict__ Amh, const _Float16* __restrict__ Aml,
               float* __restrict__ pp0, float* __restrict__ pp1,
               float* __restrict__ eqpart, const float* __restrict__ bp,
               const int* __restrict__ guard)
{
  if (guard[0]) return;
  const int tile = (int)blockIdx.x;
  const bool is_eq = tile < 32;
  const int kz = (int)blockIdx.z;
  if (is_eq && kz) return;
  const int t = (int)threadIdx.x;
  const int m0 = (int)blockIdx.y * 128;
  const int n0 = is_eq ? tile*64 : (tile-32)*64;
  const _Float16* __restrict__ Bhg = is_eq ? Amh : Wzh;
  const _Float16* __restrict__ Blg = is_eq ? Aml : Wzl;
  const int kbeg = is_eq ? 0 : kz*(NV/2);
  const int nkt  = is_eq ? NV/64 : NV/128;

  __shared__ _Float16 Ah[128][64], Al[128][64], Bs_h[64][64], Bs_l[64][64];
  __shared__ float red[2][64];

  const int lane = t & 63, wid = t >> 6;
  const int wr = wid >> 1, wc = wid & 1, lg = lane >> 5, ln = lane & 31;

  f32x16 a0[2], a1[2], a2[2];
  #pragma unroll
  for (int f=0; f<2; ++f)
    #pragma unroll
    for (int i=0;i<16;i++){ a0[f][i]=0.f; a1[f][i]=0.f; a2[f][i]=0.f; }

  float4 rAh[4], rAl[4], rBh[2], rBl[2];

  auto gload = [&](int kt){
    const int k0 = kbeg + kt*64;
    #pragma unroll
    for (int q=0;q<4;q++){
      const int idx = q*256 + t;
      const int r = idx>>3, ch = idx&7;
      const size_t off = (size_t)(m0+r)*NV + k0 + ch*8;
      rAh[q] = *reinterpret_cast<const float4*>(&zh[off]);
      rAl[q] = *reinterpret_cast<const float4*>(&zl[off]);
    }
    #pragma unroll
    for (int q=0;q<2;q++){
      const int idx = q*256 + t;
      const int r = idx>>3, ch = idx&7;
      const size_t off = (size_t)(n0+r)*NV + k0 + ch*8;
      rBh[q] = *reinterpret_cast<const float4*>(&Bhg[off]);
      rBl[q] = *reinterpret_cast<const float4*>(&Blg[off]);
    }
  };
  auto sstore = [&](int kt){
    const int k0 = kbeg + kt*64;
    const bool rl = (!is_eq) && (k0 >= FREEN);
    #pragma unroll
    for (int q=0;q<4;q++){
      const int idx = q*256 + t;
      const int r = idx>>3, ch = idx&7;
      float4 vh = rAh[q], vl = rAl[q];
      if (rl){
        half8 hh = *reinterpret_cast<half8*>(&vh);
        half8 ll = *reinterpret_cast<half8*>(&vl);
        #pragma unroll
        for (int j=0;j<8;j++){
          const _Float16 h = hh[j], l = ll[j];
          if (h < (_Float16)0.f || (h == (_Float16)0.f && l < (_Float16)0.f)){
            hh[j] = (_Float16)0.f; ll[j] = (_Float16)0.f;
          }
        }
        vh = *reinterpret_cast<float4*>(&hh);
        vl = *reinterpret_cast<float4*>(&ll);
      }
      const int sc = (ch ^ (r&7))*8;
      *reinterpret_cast<float4*>(&Ah[r][sc]) = vh;
      *reinterpret_cast<float4*>(&Al[r][sc]) = vl;
    }
    #pragma unroll
    for (int q=0;q<2;q++){
      const int idx = q*256 + t;
      const int r = idx>>3, ch = idx&7;
      const int sc = (ch ^ (r&7))*8;
      *reinterpret_cast<float4*>(&Bs_h[r][sc]) = rBh[q];
      *reinterpret_cast<float4*>(&Bs_l[r][sc]) = rBl[q];
    }
  };

  gload(0);
  for (int kt=0; kt<nkt; ++kt){
    __syncthreads();
    sstore(kt);
    __syncthreads();
    if (kt+1 < nkt) gload(kt+1);
    const int brow = wc*32 + ln;
    #pragma unroll
    for (int s=0;s<4;s++){
      const int cb = ((s*2+lg) ^ (brow&7))*8;
      const half8 bh = *reinterpret_cast<const half8*>(&Bs_h[brow][cb]);
      const half8 bl = *reinterpret_cast<const half8*>(&Bs_l[brow][cb]);
      #pragma unroll
      for (int f=0; f<2; ++f){
        const int arow = wr*64 + f*32 + ln;
        const int ca = ((s*2+lg) ^ (arow&7))*8;
        const half8 ah = *reinterpret_cast<const half8*>(&Ah[arow][ca]);
        const half8 al = *reinterpret_cast<const half8*>(&Al[arow][ca]);
        a0[f] = __builtin_amdgcn_mfma_f32_32x32x16_f16(ah, bh, a0[f], 0, 0, 0);
        a1[f] = __builtin_amdgcn_mfma_f32_32x32x16_f16(ah, bl, a1[f], 0, 0, 0);
        a2[f] = __builtin_amdgcn_mfma_f32_32x32x16_f16(al, bh, a2[f], 0, 0, 0);
      }
    }
  }

  if (is_eq){
    float s = 0.f;
    #pragma unroll
    for (int f=0; f<2; ++f)
      #pragma unroll
      for (int r16=0;r16<16;r16++){
        const int row = (r16&3) + 8*(r16>>2) + 4*lg;   // verified 32x32 C/D mapping
        const int gm = m0 + wr*64 + f*32 + row;
        const int gn = n0 + wc*32 + ln;
        float v = a0[f][r16] + (a1[f][r16]+a2[f][r16])*(1.f/2048.f);
        v -= bp[(size_t)gm*MC + gn];
        s += fabsf(v);
      }
    s += __shfl_xor(s, 32, 64);
    if (lg==0) red[wr][wc*32+ln] = s;
    __syncthreads();
    if (t < 64) eqpart[(size_t)blockIdx.y*MC + n0 + t] = red[0][t] + red[1][t];
  } else {
    float* __restrict__ pp = kz ? pp1 : pp0;
    #pragma unroll
    for (int f=0; f<2; ++f)
      #pragma unroll
      for (int r16=0;r16<16;r16++){
        const int row = (r16&3) + 8*(r16>>2) + 4*lg;
        const int gm = m0 + wr*64 + f*32 + row;
        const int gn = n0 + wc*32 + ln;
        pp[(size_t)gm*NV + gn] = a0[f][r16] + (a1[f][r16]+a2[f][r16])*(1.f/2048.f);
      }
  }
}

// combine: z = pp0+pp1+Bias -> split pair + ineq column partials (16 row-groups)
__global__ __launch_bounds__(256)
void combine_k(const float* __restrict__ pp0, const float* __restrict__ pp1,
               const float* __restrict__ BiasM,
               _Float16* __restrict__ zh, _Float16* __restrict__ zl,
               float* __restrict__ ineqpart, const int* __restrict__ guard)
{
  if (guard[0]) return;
  const int c = blockIdx.x*256 + threadIdx.x;
  const int rb = blockIdx.y;
  float acc = 0.f;
  for (int r=0; r<16; ++r){
    const size_t idx = (size_t)(rb*16+r)*NV + c;
    const float z = pp0[idx] + pp1[idx] + BiasM[idx];
    _Float16 h, l; split_f32(z, h, l);
    zh[idx] = h; zl[idx] = l;
    acc += fmaxf(-z, 0.f);
  }
  ineqpart[(size_t)rb*NV + c] = acc;
}

__global__ __launch_bounds__(256)
void check2_k(const float* __restrict__ eqpart, const float* __restrict__ ineqpart,
              int* __restrict__ viol, const int* __restrict__ done)
{
  if (done[0]) return;
  const int id = blockIdx.x*256 + threadIdx.x;
  bool bad;
  if (id < MC){
    const float s = eqpart[id] + eqpart[MC + id];
    bad = (s*(1.f/(float)BSZ) > TOLF);
  } else {
    const int c = FREEN + (id - MC);
    float s = 0.f;
    #pragma unroll
    for (int g=0; g<16; g++) s += ineqpart[(size_t)g*NV + c];
    bad = (s*(1.f/(float)BSZ) > TOLF);
  }
  if (bad) atomicAdd(viol, 1);
}

// ---------------- LayerNorm ----------------
__global__ __launch_bounds__(256)
void ln_k(float* __restrict__ x, const float* __restrict__ g, const float* __restrict__ b)
{
  const int row = blockIdx.x, t = threadIdx.x;
  float4 v = *reinterpret_cast<const float4*>(&x[(size_t)row*HID + t*4]);
  __shared__ float sm[256];
  sm[t] = v.x+v.y+v.z+v.w;
  __syncthreads();
  for (int st=128; st>0; st>>=1){ if (t<st) sm[t]+=sm[t+st]; __syncthreads(); }
  const float mu = sm[0]*(1.f/(float)HID);
  __syncthreads();
  const float dx=v.x-mu, dy=v.y-mu, dz=v.z-mu, dw=v.w-mu;
  sm[t] = dx*dx+dy*dy+dz*dz+dw*dw;
  __syncthreads();
  for (int st=128; st>0; st>>=1){ if (t<st) sm[t]+=sm[t+st]; __syncthreads(); }
  const float inv = 1.f/sqrtf(sm[0]*(1.f/(float)HID) + 1e-5f);
  const int c = t*4;
  const float4 gv = *reinterpret_cast<const float4*>(&g[c]);
  const float4 bv = *reinterpret_cast<const float4*>(&b[c]);
  float4 o;
  o.x = dx*inv*gv.x + bv.x; o.y = dy*inv*gv.y + bv.y;
  o.z = dz*inv*gv.z + bv.z; o.w = dw*inv*gv.w + bv.w;
  *reinterpret_cast<float4*>(&x[(size_t)row*HID + c]) = o;
}

// ---------------- fallback convergence machinery (f32 path) ----------------
__global__ __launch_bounds__(256)
void check_k(const float* __restrict__ eqpart, const float* __restrict__ znew,
             int* __restrict__ viol, const int* __restrict__ done, int ngroups)
{
  if (done[0]) return;
  const int id = blockIdx.x*256 + threadIdx.x;
  bool bad;
  if (id < MC){
    float s = 0.f;
    for (int g=0; g<ngroups; g++) s += eqpart[g*MC + id];
    bad = (s*(1.f/(float)BSZ) > TOLF);
  } else {
    const int c = FREEN + (id - MC);
    float s = 0.f;
    for (int r=0; r<BSZ; r++){
      const float v = znew[(size_t)r*NV + c];
      s += (v < 0.f) ? -v : 0.f;
    }
    bad = (s*(1.f/(float)BSZ) > TOLF);
  }
  if (bad) atomicAdd(viol, 1);
}

__global__ void init_k(int* flags){ flags[0]=0; flags[1]=0; flags[2]=0; }

__global__ void update_k(int* flags){
  if (!flags[0]){ flags[1] += 1; if (flags[2]==0) flags[0]=1; }
  flags[2] = 0;
}

__global__ __launch_bounds__(256)
void final_k(const float* __restrict__ buf1, float* __restrict__ out, const int* __restrict__ flags)
{
  const int i = blockIdx.x*256 + threadIdx.x;
  const int k = flags[1];
  if ((k & 1) && i < BSZ*NV) out[i] = buf1[i];
  if (i == 0) out[2*BSZ*NV] = (float)k;
}

// fp16 path: reconstruct z_star from the winning pair (h + l/2048, error ~1e-5)
__global__ __launch_bounds__(256)
void final16_k(const _Float16* __restrict__ zh0, const _Float16* __restrict__ zl0,
               const _Float16* __restrict__ zh1, const _Float16* __restrict__ zl1,
               float* __restrict__ out, const int* __restrict__ flags)
{
  const int i = blockIdx.x*256 + threadIdx.x;
  const int k = flags[1];
  const _Float16* h = (k & 1) ? zh1 : zh0;
  const _Float16* l = (k & 1) ? zl1 : zl0;
  out[i] = (float)h[i] + (float)l[i]*(1.f/2048.f);
  if (i == 0) out[2*BSZ*NV] = (float)k;
}

// ---------------- host launch ----------------
extern "C" void kernel_launch(void* const* d_in, const int* in_sizes, int n_in,
                              void* d_out, int out_size, void* d_ws, size_t ws_size,
                              hipStream_t stream)
{
  const float* bp  = (const float*)d_in[0];
  const float* w1  = (const float*)d_in[1];
  const float* b1  = (const float*)d_in[2];
  const float* g1  = (const float*)d_in[3];
  const float* be1 = (const float*)d_in[4];
  const float* w2  = (const float*)d_in[5];
  const float* b2  = (const float*)d_in[6];
  const float* g2  = (const float*)d_in[7];
  const float* be2 = (const float*)d_in[8];
  const float* w3  = (const float*)d_in[9];
  const float* b3  = (const float*)d_in[10];
  const float* g3  = (const float*)d_in[11];
  const float* be3 = (const float*)d_in[12];
  const float* wo  = (const float*)d_in[13];
  const float* bo  = (const float*)d_in[14];
  const float* A   = (const float*)d_in[15];
  const float* Wz  = (const float*)d_in[16];
  const float* Wb  = (const float*)d_in[17];

  float* out  = (float*)d_out;
  float* z0   = out + (size_t)BSZ*NV;
  float* buf0 = out;

  float* ws       = (float*)d_ws;
  float* tmp1     = ws;                            // 256*1024
  float* tmp2     = tmp1 + (size_t)BSZ*HID;        // 256*1024
  float* BiasM    = tmp2 + (size_t)BSZ*HID;        // 256*4096
  float* buf1     = BiasM + (size_t)BSZ*NV;        // 256*4096 (fallback)
  float* eqpart   = buf1 + (size_t)BSZ*NV;         // 8*2048 (fallback uses 8; fp16 uses 2)
  float* ineqpart = eqpart + 8*MC;                 // 16*4096
  float* pp0      = ineqpart + (size_t)16*NV;      // 256*4096
  float* pp1      = pp0 + (size_t)BSZ*NV;          // 256*4096
  int*   flags    = (int*)(pp1 + (size_t)BSZ*NV);  // 4 ints

  _Float16* Wzh = (_Float16*)(flags + 4);
  _Float16* Wzl = Wzh + (size_t)NV*NV;
  _Float16* Amh = Wzl + (size_t)NV*NV;
  _Float16* Aml = Amh + (size_t)MC*NV;
  _Float16* zh0 = Aml + (size_t)MC*NV;
  _Float16* zl0 = zh0 + (size_t)BSZ*NV;
  _Float16* zh1 = zl0 + (size_t)BSZ*NV;
  _Float16* zl1 = zh1 + (size_t)BSZ*NV;
  const size_t need = (size_t)((char*)(zl1 + (size_t)BSZ*NV) - (char*)d_ws);
  const bool fp16path = (ws_size >= need);

  const dim3 blk(256);

  hipLaunchKernelGGL(init_k, dim3(1), dim3(1), 0, stream, flags);

  // ---- MLP + projection-setup (f32, one-time) ----
  hipLaunchKernelGGL((gemm_k<64,64,32,4,4,false,false,EPI_BIASRELU>), dim3(HID/64, BSZ/64), blk, 0, stream,
                     bp, MC, w1, HID, tmp1, MC, HID, b1, nullptr, 0, nullptr);
  hipLaunchKernelGGL(ln_k, dim3(BSZ), blk, 0, stream, tmp1, g1, be1);
  hipLaunchKernelGGL((gemm_k<64,64,32,4,4,false,false,EPI_BIASRELU>), dim3(HID/64, BSZ/64), blk, 0, stream,
                     tmp1, HID, w2, HID, tmp2, HID, HID, b2, nullptr, 0, nullptr);
  hipLaunchKernelGGL(ln_k, dim3(BSZ), blk, 0, stream, tmp2, g2, be2);
  hipLaunchKernelGGL((gemm_k<64,64,32,4,4,false,false,EPI_BIASRELU>), dim3(HID/64, BSZ/64), blk, 0, stream,
                     tmp2, HID, w3, HID, tmp1, HID, HID, b3, nullptr, 0, nullptr);
  hipLaunchKernelGGL(ln_k, dim3(BSZ), blk, 0, stream, tmp1, g3, be3);
  hipLaunchKernelGGL((gemm_k<64,64,32,4,4,false,false,EPI_BIAS>), dim3(NV/64, BSZ/64), blk, 0, stream,
                     tmp1, HID, wo, NV, z0, HID, NV, bo, nullptr, 0, nullptr);
  hipLaunchKernelGGL((gemm_k<64,64,32,4,4,true,false,EPI_NONE>), dim3(NV/64, BSZ/64), blk, 0, stream,
                     bp, MC, Wb, MC, BiasM, MC, NV, nullptr, nullptr, 0, nullptr);
  hipLaunchKernelGGL((gemm_k<64,64,32,4,4,true,false,EPI_ADDMAT>), dim3(NV/64, BSZ/64), blk, 0, stream,
                     z0, NV, Wz, NV, buf0, NV, NV, nullptr, BiasM, NV, nullptr);

  if (fp16path){
    // one-time fp16x2 splits
    hipLaunchKernelGGL(split_k, dim3((NV*(size_t)NV)/1024), blk, 0, stream, Wz, Wzh, Wzl, (int)((NV*(size_t)NV)/4));
    hipLaunchKernelGGL(split_k, dim3((MC*(size_t)NV)/1024), blk, 0, stream, A,  Amh, Aml, (int)((MC*(size_t)NV)/4));
    hipLaunchKernelGGL(split_k, dim3((BSZ*(size_t)NV)/1024), blk, 0, stream, buf0, zh0, zl0, (int)((BSZ*(size_t)NV)/4));

    const dim3 fgrid(96, 2, 2);
    // round 1: fused (eqpart result unused), combine -> z1 in pair1 + ineq1
    hipLaunchKernelGGL(fused16_k, fgrid, blk, 0, stream,
                       zh0, zl0, Wzh, Wzl, Amh, Aml, pp0, pp1, eqpart, bp, flags);
    hipLaunchKernelGGL(combine_k, dim3(NV/256, 16), blk, 0, stream,
                       pp0, pp1, BiasM, zh1, zl1, ineqpart, flags);

    for (int j=2; j<=NITER; ++j){
      const _Float16* sh = ((j-1)&1) ? zh1 : zh0;
      const _Float16* sl = ((j-1)&1) ? zl1 : zl0;
      _Float16* dh = (j&1) ? zh1 : zh0;
      _Float16* dl = (j&1) ? zl1 : zl0;
      // fused_j: eq of z_{j-1} + proj partials for z_j
      hipLaunchKernelGGL(fused16_k, fgrid, blk, 0, stream,
                         sh, sl, Wzh, Wzl, Amh, Aml, pp0, pp1, eqpart, bp, flags);
      // check_{j-1} + update_{j-1}
      hipLaunchKernelGGL(check2_k, dim3((MC + (NV-FREEN))/256), blk, 0, stream, eqpart, ineqpart, flags+2, flags);
      hipLaunchKernelGGL(update_k, dim3(1), dim3(1), 0, stream, flags);
      // combine_j (guarded): z_j pair + ineq_j
      hipLaunchKernelGGL(combine_k, dim3(NV/256, 16), blk, 0, stream,
                         pp0, pp1, BiasM, dh, dl, ineqpart, flags);
    }
    // tail: eq of z_31 (pair index 31&1 = 1), then check_31/update_31
    hipLaunchKernelGGL(fused16_k, dim3(32, 2, 1), blk, 0, stream,
                       zh1, zl1, Wzh, Wzl, Amh, Aml, pp0, pp1, eqpart, bp, flags);
    hipLaunchKernelGGL(check2_k, dim3((MC + (NV-FREEN))/256), blk, 0, stream, eqpart, ineqpart, flags+2, flags);
    hipLaunchKernelGGL(update_k, dim3(1), dim3(1), 0, stream, flags);

    hipLaunchKernelGGL(final16_k, dim3((BSZ*NV)/256), blk, 0, stream, zh0, zl0, zh1, zl1, out, flags);
  } else {
    // fallback: proven f32 loop
    for (int j=1; j<=NITER; ++j){
      float* src = (j&1) ? buf0 : buf1;
      float* dst = (j&1) ? buf1 : buf0;
      hipLaunchKernelGGL((gemm_k<64,64,32,4,4,true,true,EPI_ADDMAT>), dim3(NV/64, BSZ/64), blk, 0, stream,
                         src, NV, Wz, NV, dst, NV, NV, nullptr, BiasM, NV, flags);
      hipLaunchKernelGGL((gemm_k<32,64,32,2,4,true,false,EPI_EQ>), dim3(MC/64, BSZ/32), blk, 0, stream,
                         dst, NV, A, NV, eqpart, NV, MC, nullptr, bp, MC, flags);
      hipLaunchKernelGGL(check_k, dim3((MC + (NV-FREEN))/256), blk, 0, stream, eqpart, dst, flags+2, flags, 8);
      hipLaunchKernelGGL(update_k, dim3(1), dim3(1), 0, stream, flags);
    }
    hipLaunchKernelGGL(final_k, dim3((BSZ*NV)/256), blk, 0, stream, buf1, out, flags);
  }

  (void)in_sizes; (void)n_in; (void)out_size; (void)ws_size;
}